// Round 3
// baseline (607.962 us; speedup 1.0000x reference)
//
#include <hip/hip_runtime.h>

typedef unsigned long long u64;
typedef __attribute__((ext_vector_type(8))) short short8;
typedef __attribute__((ext_vector_type(4))) float f32x4;

#define PP 65536
#define CC 21
#define EMB_SCALE_F 9.76762622f
#define NID 1000

// ---- workspace layout (bytes) ----
#define OFF_KEYS   0ull            // u64[8*65536]  = 4MB
#define OFF_HIST   4194304ull      // u32[8*65536]  = 2MB ; reused as cand u64[8][32768]
#define OFF_WSWZ   6291456ull      // bf16 pre-swizzled W: 32 tiles x 16KB = 512KB
#define OFF_STATE  6815744ull
#define ST_NUMPOS   0    // int[8]
#define ST_CANDCNT  32   // u32[8]
#define ST_KTHHI    64   // u32[8]
#define ST_KREM     96   // u32[8]
#define ST_DONE     128  // u32[8]
#define ST_KTH      160  // u64[8]
#define ST_ACCUM    224  // float[2]
#define ST_WORDS    58

__device__ __forceinline__ unsigned short f2bf(float f) {
    unsigned u = __float_as_uint(f);
    u = (u + 0x7FFFu + ((u >> 16) & 1u)) >> 16;   // RNE
    return (unsigned short)u;
}

__device__ __forceinline__ float bf2f(short s) {
    return __uint_as_float((unsigned)(unsigned short)s << 16);
}

__device__ __forceinline__ void gl_lds16(const void* g, void* l) {
    __builtin_amdgcn_global_load_lds((const __attribute__((address_space(1))) unsigned*)g,
                                     (__attribute__((address_space(3))) unsigned*)l, 16, 0, 0);
}

// ---------------- prep: zero hist+state, W -> pre-swizzled bf16 (32-row tiles) ----------------
__global__ void k_prep(const float* __restrict__ Wm, unsigned short* __restrict__ wswz,
                       unsigned* __restrict__ hist, unsigned* __restrict__ state) {
    int idx = blockIdx.x * 256 + threadIdx.x;    // grid = 524288 exactly
    hist[idx] = 0u;
    if (idx < ST_WORDS) state[idx] = 0u;
    if (idx < 32768) {                            // 16B granules of the 512KB image
        int c    = idx & 31;
        int row  = (idx >> 5) & 31;
        int tile = idx >> 10;
        int cls  = tile * 32 + row;
        ushort4 h0, h1;
        h0.x = h0.y = h0.z = h0.w = 0;
        h1.x = h1.y = h1.z = h1.w = 0;
        if (cls < NID) {
            int srcByte = (c << 4) ^ ((row & 7) << 4);
            const float* s = Wm + (size_t)cls * 256 + (srcByte >> 1);
            float4 a = *(const float4*)s;
            float4 b = *(const float4*)(s + 4);
            h0.x = f2bf(a.x); h0.y = f2bf(a.y); h0.z = f2bf(a.z); h0.w = f2bf(a.w);
            h1.x = f2bf(b.x); h1.y = f2bf(b.y); h1.z = f2bf(b.z); h1.w = f2bf(b.w);
        }
        ushort4* dst = (ushort4*)((char*)wswz + ((size_t)idx << 4));
        dst[0] = h0; dst[1] = h1;
    }
}

// ---------------- bg_loss -> keys + numPos + 16-bit histogram (LDS-staged conf) ----------------
__global__ void k_keys(const float* __restrict__ conf, const int* __restrict__ labels,
                       u64* __restrict__ keys, int* __restrict__ numPos,
                       unsigned* __restrict__ hist) {
    __shared__ float cs[5376];                   // 256 priors x 21 floats
    int tid = threadIdx.x, blk = blockIdx.x;
    const float4* src = (const float4*)(conf + (size_t)blk * 5376);
#pragma unroll
    for (int it = 0; it < 6; ++it) {
        int g = tid + (it << 8);
        if (g < 1344) ((float4*)cs)[g] = src[g];
    }
    __syncthreads();
    int idx = blk * 256 + tid;
    int b = idx >> 16;
    int p = idx & 65535;
    const float* c = cs + tid * 21;
    float x0 = c[0];
    float m = x0;
#pragma unroll
    for (int j = 1; j < CC; ++j) m = fmaxf(m, c[j]);
    float s = 0.f;
#pragma unroll
    for (int j = 0; j < CC; ++j) s += __expf(c[j] - m);
    float bg = m + __logf(s) - x0;
    bool pos = labels[idx] > 0;
    unsigned u = __float_as_uint(bg);
    u = (u & 0x80000000u) ? ~u : (u | 0x80000000u);
    u64 key = pos ? 0ull : ((((u64)u) << 32) | (u64)(0xFFFFFFFFu - (unsigned)p));
    keys[idx] = key;
    if (key) atomicAdd(&hist[(b << 16) + (int)(key >> 48)], 1u);
    u64 bal = __ballot(pos);
    if ((tid & 63) == 0) {
        int cnt = __popcll(bal);
        if (cnt) atomicAdd(&numPos[b], cnt);
    }
}

// ---------------- parallel suffix-scan over 64K bins: pick top-16-bit digit ----------------
__global__ void k_scan0(const unsigned* __restrict__ hist, const int* __restrict__ numPos,
                        unsigned* __restrict__ kthHi, unsigned* __restrict__ kRem,
                        unsigned* __restrict__ done, u64* __restrict__ kth) {
    int b = blockIdx.x, t = threadIdx.x;   // 8 blocks x 1024
    __shared__ unsigned s[1024];
    __shared__ unsigned sh_c, sh_kk;
    int np = numPos[b];
    long long kk64 = (long long)np * 15;
    long long neg = (long long)PP - np;
    if (kk64 > neg) kk64 = neg;
    unsigned k = (unsigned)kk64;
    if (k == 0) { if (t == 0) { done[b] = 1u; kth[b] = ~0ull; } return; }
    const unsigned* h = hist + (b << 16);
    unsigned cs = 0;
    const uint4* hv = (const uint4*)(h + (t << 6));
#pragma unroll
    for (int j = 0; j < 16; ++j) { uint4 v = hv[j]; cs += v.x + v.y + v.z + v.w; }
    s[t] = cs; __syncthreads();
    for (int off = 1; off < 1024; off <<= 1) {
        unsigned v = (t + off < 1024) ? s[t + off] : 0u;
        __syncthreads(); s[t] += v; __syncthreads();
    }
    unsigned si = s[t];
    if (si >= k && si - cs < k) { sh_c = (unsigned)t; sh_kk = k - (si - cs); }
    __syncthreads();
    if (t < 64) {
        unsigned c = sh_c, kk = sh_kk;
        unsigned bin = h[(c << 6) + t];
        unsigned sfx = bin;
        for (int off = 1; off < 64; off <<= 1) {
            unsigned v = __shfl_down(sfx, off, 64);
            if (t + off < 64) sfx += v;
        }
        if (sfx >= kk && sfx - bin < kk) {
            kthHi[b] = (c << 6) | (unsigned)t;
            kRem[b]  = kk - (sfx - bin);
        }
    }
}

// ---------------- compact keys matching the selected top-16 digit ----------------
__global__ void k_compact(const u64* __restrict__ keys, const unsigned* __restrict__ kthHi,
                          const unsigned* __restrict__ done, u64* __restrict__ cand,
                          unsigned* __restrict__ candCnt) {
    int idx = blockIdx.x * 256 + threadIdx.x;
    int b = idx >> 16;
    if (done[b]) return;
    u64 key = keys[idx];
    if ((unsigned)(key >> 48) == kthHi[b]) {
        unsigned pos = atomicAdd(&candCnt[b], 1u);
        if (pos < 32768u) cand[((size_t)b << 15) + pos] = key;
    }
}

// ---------------- in-block radix over low 48 bits -> exact kth key ----------------
__global__ void k_select2(const u64* __restrict__ cand, const unsigned* __restrict__ candCnt,
                          const unsigned* __restrict__ kthHi, const unsigned* __restrict__ kRem,
                          const unsigned* __restrict__ done, u64* __restrict__ kth) {
    int b = blockIdx.x, t = threadIdx.x;   // 8 blocks x 256
    if (done[b]) return;
    __shared__ unsigned wh[4][256];
    __shared__ unsigned s[256];
    __shared__ u64 sh_pref;
    __shared__ unsigned sh_kk;
    int wv = t >> 6;
    unsigned n = candCnt[b]; if (n > 32768u) n = 32768u;
    if (t == 0) { sh_pref = 0ull; sh_kk = kRem[b]; }
    __syncthreads();
    const u64* cb = cand + ((size_t)b << 15);
    for (int pass = 0; pass < 6; ++pass) {
        int shift = 40 - 8 * pass;
        wh[0][t] = 0u; wh[1][t] = 0u; wh[2][t] = 0u; wh[3][t] = 0u;
        __syncthreads();
        u64 pref = sh_pref; unsigned kk = sh_kk;
        u64 himask = (~((1ull << (shift + 8)) - 1ull)) & 0x0000FFFFFFFFFFFFull;
        for (unsigned i = t; i < n; i += 256) {
            u64 kv = cb[i] & 0x0000FFFFFFFFFFFFull;
            if ((kv & himask) == pref)
                atomicAdd(&wh[wv][(unsigned)(kv >> shift) & 255u], 1u);
        }
        __syncthreads();
        unsigned hsum = wh[0][t] + wh[1][t] + wh[2][t] + wh[3][t];
        s[t] = hsum; __syncthreads();
        for (int off = 1; off < 256; off <<= 1) {
            unsigned v = (t + off < 256) ? s[t + off] : 0u;
            __syncthreads(); s[t] += v; __syncthreads();
        }
        unsigned si = s[t];
        if (si >= kk && si - hsum < kk) {
            sh_pref = pref | ((u64)t << shift);
            sh_kk = kk - (si - hsum);
        }
        __syncthreads();
    }
    if (t == 0) kth[b] = ((u64)kthHi[b] << 48) | sh_pref;
}

// ---------------- fused normalize + MFMA GEMM + logsumexp CE ----------------
// M=128/block, N-tiles of 32, direct-from-global A fragments, post-MFMA row scaling,
// W double-buffered via gl_lds with counted vmcnt. LDS 39KB -> 4 blocks/CU.
__launch_bounds__(256, 4)
__global__ void k_ce(const float* __restrict__ pid, const int* __restrict__ labels,
                     const int* __restrict__ gt, const unsigned short* __restrict__ wswz,
                     const float* __restrict__ bias, const u64* __restrict__ keys,
                     const u64* __restrict__ kth_, const unsigned* __restrict__ done_,
                     float* __restrict__ accum) {
    __shared__ __align__(16) char Ws[32768];      // W double buffer: 2 x (32 rows x 512B)
    __shared__ float biasLds[1024];
    __shared__ int gid_s[128];
    __shared__ float mask_s[128];
    __shared__ float fsum[128];
    __shared__ float fgl[128];

    int tid = threadIdx.x;
    int blk = blockIdx.x;              // 1024
    int b = blk >> 7;
    int locBase = (blk & 127) << 7;
    int wv = tid >> 6, lane = tid & 63;
    int l15 = lane & 15, l4 = lane >> 4;
    int kb = l4 << 4;

    // ---- A fragments direct from global (raw bf16) + row norms ----
    short8 af[2][8];
    float rs[2];
    const char* Xb = (const char*)pid + (((size_t)b * 16384 + (size_t)locBase) << 10);
#pragma unroll
    for (int ci = 0; ci < 2; ++ci) {
        const char* xr = Xb + (((size_t)(wv * 32 + ci * 16 + l15)) << 10) + (l4 << 5);
        float ss = 0.f;
#pragma unroll
        for (int ks = 0; ks < 8; ++ks) {
            float4 a  = *(const float4*)(xr + (ks << 7));
            float4 c2 = *(const float4*)(xr + (ks << 7) + 16);
            ss += a.x*a.x + a.y*a.y + a.z*a.z + a.w*a.w
                + c2.x*c2.x + c2.y*c2.y + c2.z*c2.z + c2.w*c2.w;
            short8 v;
            v[0] = (short)f2bf(a.x);  v[1] = (short)f2bf(a.y);
            v[2] = (short)f2bf(a.z);  v[3] = (short)f2bf(a.w);
            v[4] = (short)f2bf(c2.x); v[5] = (short)f2bf(c2.y);
            v[6] = (short)f2bf(c2.z); v[7] = (short)f2bf(c2.w);
            af[ci][ks] = v;
        }
        ss += __shfl_xor(ss, 16, 64);
        ss += __shfl_xor(ss, 32, 64);
        rs[ci] = EMB_SCALE_F / fmaxf(sqrtf(ss), 1e-12f);
    }
    float sc[2][4];
#pragma unroll
    for (int ci = 0; ci < 2; ++ci)
#pragma unroll
        for (int reg = 0; reg < 4; ++reg)
            sc[ci][reg] = __shfl(rs[ci], (l4 << 2) + reg, 64);

    // ---- metadata ----
    if (tid < 128) {
        size_t pb = (size_t)b * PP + ((size_t)(locBase + tid) << 2);
        int g0 = gt[pb], g1 = gt[pb + 1], g2 = gt[pb + 2], g3 = gt[pb + 3];
        int gid = max(max(g0, g1), max(g2, g3));
        u64 kth = kth_[b];
        unsigned dn = done_[b];
        unsigned msk = 0;
#pragma unroll
        for (int a = 0; a < 4; ++a)
            if (labels[pb + a] > 0 || (!dn && keys[pb + a] >= kth)) msk = 1u;
        if (gid < 0) msk = 0;
        gid_s[tid] = min(max(gid, 0), NID - 1);
        mask_s[tid] = (float)msk;
    }
#pragma unroll
    for (int i = 0; i < 4; ++i) {
        int idx = tid + (i << 8);
        biasLds[idx] = (idx < NID) ? bias[idx] : -INFINITY;
    }

    // ---- issue W tiles 0,1 (last vmem before loop -> counted vmcnt stays exact) ----
    {
        const char* g0 = (const char*)wswz + (wv << 12) + (lane << 4);
        char* l0 = Ws + (wv << 12);
#pragma unroll
        for (int it = 0; it < 4; ++it) gl_lds16(g0 + (it << 10), l0 + (it << 10));
#pragma unroll
        for (int it = 0; it < 4; ++it) gl_lds16(g0 + 16384 + (it << 10), l0 + 16384 + (it << 10));
    }

    asm volatile("s_waitcnt lgkmcnt(0)" ::: "memory");   // LDS writes visible at first barrier

    float runsum[2][4];
#pragma unroll
    for (int ci = 0; ci < 2; ++ci)
#pragma unroll
        for (int reg = 0; reg < 4; ++reg) runsum[ci][reg] = 0.f;

    int swz = (l15 & 7) << 4;
    const char* r0base = Ws + l15 * 512;
    const char* r1base = Ws + (l15 + 16) * 512;

#pragma unroll 1
    for (int nt = 0; nt < 32; ++nt) {
        if (nt == 31) asm volatile("s_waitcnt vmcnt(0)" ::: "memory");
        else          asm volatile("s_waitcnt vmcnt(4)" ::: "memory");
        asm volatile("s_barrier" ::: "memory");
        int p = (nt & 1) << 14;

        f32x4 a00 = {0,0,0,0}, a01 = {0,0,0,0}, a10 = {0,0,0,0}, a11 = {0,0,0,0};
#pragma unroll
        for (int ks = 0; ks < 8; ++ks) {
            int off = ((((ks << 6) + kb)) ^ swz) + p;
            short8 b0 = *(const short8*)(r0base + off);
            short8 b1 = *(const short8*)(r1base + off);
            a00 = __builtin_amdgcn_mfma_f32_16x16x32_bf16(af[0][ks], b0, a00, 0, 0, 0);
            a01 = __builtin_amdgcn_mfma_f32_16x16x32_bf16(af[0][ks], b1, a01, 0, 0, 0);
            a10 = __builtin_amdgcn_mfma_f32_16x16x32_bf16(af[1][ks], b0, a10, 0, 0, 0);
            a11 = __builtin_amdgcn_mfma_f32_16x16x32_bf16(af[1][ks], b1, a11, 0, 0, 0);
        }
        asm volatile("s_barrier" ::: "memory");           // buf p free for overwrite

        if (nt < 30) {
            const char* gs = (const char*)wswz + ((size_t)(nt + 2) << 14) + (wv << 12) + (lane << 4);
            char* ls = Ws + p + (wv << 12);
#pragma unroll
            for (int it = 0; it < 4; ++it) gl_lds16(gs + (it << 10), ls + (it << 10));
        }

        float bl0 = biasLds[(nt << 5) + l15];
        float bl1 = biasLds[(nt << 5) + 16 + l15];
#pragma unroll
        for (int reg = 0; reg < 4; ++reg) {
            runsum[0][reg] += __expf(fmaf(a00[reg], sc[0][reg], bl0))
                            + __expf(fmaf(a01[reg], sc[0][reg], bl1));
            runsum[1][reg] += __expf(fmaf(a10[reg], sc[1][reg], bl0))
                            + __expf(fmaf(a11[reg], sc[1][reg], bl1));
        }
    }

    // ---- reduce runsum across the 16-lane column groups; direct store (no atomics) ----
#pragma unroll
    for (int o = 1; o <= 8; o <<= 1)
#pragma unroll
        for (int ci = 0; ci < 2; ++ci)
#pragma unroll
            for (int reg = 0; reg < 4; ++reg)
                runsum[ci][reg] += __shfl_xor(runsum[ci][reg], o, 64);
    if (l15 == 0) {
#pragma unroll
        for (int ci = 0; ci < 2; ++ci)
#pragma unroll
            for (int reg = 0; reg < 4; ++reg)
                fsum[wv * 32 + ci * 16 + (l4 << 2) + reg] = runsum[ci][reg];
    }

    // ---- gid-logit via register dot against global W row ----
#pragma unroll
    for (int ci = 0; ci < 2; ++ci) {
        int gid = gid_s[wv * 32 + ci * 16 + l15];
        const char* wr = (const char*)wswz + ((size_t)(gid >> 5) << 14) + ((size_t)(gid & 31) << 9);
        int gsw = (gid & 7) << 4;
        float d = 0.f;
#pragma unroll
        for (int ks = 0; ks < 8; ++ks) {
            short8 w8 = *(const short8*)(wr + ((((ks << 6) + kb)) ^ gsw));
            short8 a8 = af[ci][ks];
#pragma unroll
            for (int j = 0; j < 8; ++j) d = fmaf(bf2f(a8[j]), bf2f(w8[j]), d);
        }
        d += __shfl_xor(d, 16, 64);
        d += __shfl_xor(d, 32, 64);
        if (lane < 16) fgl[wv * 32 + ci * 16 + lane] = fmaf(d, rs[ci], biasLds[gid]);
    }
    __syncthreads();

    if (tid < 128) {
        float ce = __logf(fsum[tid]) - fgl[tid];
        float mm = mask_s[tid];
        float cs2 = ce * mm;
#pragma unroll
        for (int o = 1; o <= 32; o <<= 1) {
            cs2 += __shfl_xor(cs2, o, 64);
            mm  += __shfl_xor(mm, o, 64);
        }
        if (lane == 0) {
            atomicAdd(&accum[0], cs2);
            atomicAdd(&accum[1], mm);
        }
    }
}

__global__ void k_fin(const float* __restrict__ accum, float* __restrict__ out) {
    out[0] = accum[0] / fmaxf(accum[1], 1.0f);
}

extern "C" void kernel_launch(void* const* d_in, const int* in_sizes, int n_in,
                              void* d_out, int out_size, void* d_ws, size_t ws_size,
                              hipStream_t stream) {
    (void)in_sizes; (void)n_in; (void)out_size; (void)ws_size;
    const float* conf   = (const float*)d_in[0];
    const float* pid    = (const float*)d_in[1];
    const int*   labels = (const int*)d_in[2];
    const int*   gt     = (const int*)d_in[3];
    const float* Wm     = (const float*)d_in[4];
    const float* bias   = (const float*)d_in[5];
    float* out = (float*)d_out;
    char* ws = (char*)d_ws;

    u64* keys           = (u64*)(ws + OFF_KEYS);
    unsigned* hist      = (unsigned*)(ws + OFF_HIST);
    u64* cand           = (u64*)(ws + OFF_HIST);       // reuses hist region
    unsigned short* wsw = (unsigned short*)(ws + OFF_WSWZ);
    char* st            = ws + OFF_STATE;
    int* numPos         = (int*)(st + ST_NUMPOS);
    unsigned* candCnt   = (unsigned*)(st + ST_CANDCNT);
    unsigned* kthHi     = (unsigned*)(st + ST_KTHHI);
    unsigned* kRem      = (unsigned*)(st + ST_KREM);
    unsigned* done      = (unsigned*)(st + ST_DONE);
    u64* kth            = (u64*)(st + ST_KTH);
    float* accum        = (float*)(st + ST_ACCUM);

    k_prep   <<<2048, 256, 0, stream>>>(Wm, wsw, hist, (unsigned*)st);
    k_keys   <<<2048, 256, 0, stream>>>(conf, labels, keys, numPos, hist);
    k_scan0  <<<8,   1024, 0, stream>>>(hist, numPos, kthHi, kRem, done, kth);
    k_compact<<<2048, 256, 0, stream>>>(keys, kthHi, done, cand, candCnt);
    k_select2<<<8,    256, 0, stream>>>(cand, candCnt, kthHi, kRem, done, kth);
    k_ce     <<<1024, 256, 0, stream>>>(pid, labels, gt, wsw, bias, keys, kth, done, accum);
    k_fin    <<<1, 1, 0, stream>>>(accum, out);
}

// Round 4
// 596.579 us; speedup vs baseline: 1.0191x; 1.0191x over previous
//
#include <hip/hip_runtime.h>

typedef unsigned long long u64;
typedef __attribute__((ext_vector_type(8))) short short8;
typedef __attribute__((ext_vector_type(4))) float f32x4;

#define PP 65536
#define CC 21
#define EMB_SCALE_F 9.76762622f
#define NID 1000

// ---- workspace layout (bytes) ----
#define OFF_KEYS   0ull            // u64[8*65536]  = 4MB
#define OFF_HIST   4194304ull      // u32[8*65536]  = 2MB ; phase-B reuses as cand u64[8][32768]
#define OFF_WSWZ   6291456ull      // bf16 pre-swizzled W: 32 tiles x 16KB = 512KB
#define OFF_STATE  6815744ull
#define ST_NUMPOS   0    // int[8]
#define ST_DONE     32   // u32[8]
#define ST_KTH      64   // u64[8]
#define ST_ACCUM    128  // float[2]
#define ST_FINCNT   136  // u32
#define ST_WORDS    35

__device__ __forceinline__ unsigned short f2bf(float f) {
    unsigned u = __float_as_uint(f);
    u = (u + 0x7FFFu + ((u >> 16) & 1u)) >> 16;   // RNE
    return (unsigned short)u;
}

__device__ __forceinline__ float bf2f(short s) {
    return __uint_as_float((unsigned)(unsigned short)s << 16);
}

__device__ __forceinline__ void gl_lds16(const void* g, void* l) {
    __builtin_amdgcn_global_load_lds((const __attribute__((address_space(1))) unsigned*)g,
                                     (__attribute__((address_space(3))) unsigned*)l, 16, 0, 0);
}

// ---------------- prep: zero hist+state, W -> pre-swizzled bf16 (32-row tiles) ----------------
__global__ void k_prep(const float* __restrict__ Wm, unsigned short* __restrict__ wswz,
                       unsigned* __restrict__ hist, unsigned* __restrict__ state) {
    int idx = blockIdx.x * 256 + threadIdx.x;    // grid = 524288 exactly
    hist[idx] = 0u;
    if (idx < ST_WORDS) state[idx] = 0u;
    if (idx < 32768) {                            // 16B granules of the 512KB image
        int c    = idx & 31;
        int row  = (idx >> 5) & 31;
        int tile = idx >> 10;
        int cls  = tile * 32 + row;
        ushort4 h0, h1;
        h0.x = h0.y = h0.z = h0.w = 0;
        h1.x = h1.y = h1.z = h1.w = 0;
        if (cls < NID) {
            int srcByte = (c << 4) ^ ((row & 7) << 4);
            const float* s = Wm + (size_t)cls * 256 + (srcByte >> 1);
            float4 a = *(const float4*)s;
            float4 b = *(const float4*)(s + 4);
            h0.x = f2bf(a.x); h0.y = f2bf(a.y); h0.z = f2bf(a.z); h0.w = f2bf(a.w);
            h1.x = f2bf(b.x); h1.y = f2bf(b.y); h1.z = f2bf(b.z); h1.w = f2bf(b.w);
        }
        ushort4* dst = (ushort4*)((char*)wswz + ((size_t)idx << 4));
        dst[0] = h0; dst[1] = h1;
    }
}

// ---------------- bg_loss -> keys + numPos + 16-bit histogram (LDS-staged conf) ----------------
__global__ void k_keys(const float* __restrict__ conf, const int* __restrict__ labels,
                       u64* __restrict__ keys, int* __restrict__ numPos,
                       unsigned* __restrict__ hist) {
    __shared__ float cs[5376];                   // 256 priors x 21 floats
    int tid = threadIdx.x, blk = blockIdx.x;
    const float4* src = (const float4*)(conf + (size_t)blk * 5376);
#pragma unroll
    for (int it = 0; it < 6; ++it) {
        int g = tid + (it << 8);
        if (g < 1344) ((float4*)cs)[g] = src[g];
    }
    __syncthreads();
    int idx = blk * 256 + tid;
    int b = idx >> 16;
    int p = idx & 65535;
    const float* c = cs + tid * 21;
    float x0 = c[0];
    float m = x0;
#pragma unroll
    for (int j = 1; j < CC; ++j) m = fmaxf(m, c[j]);
    float s = 0.f;
#pragma unroll
    for (int j = 0; j < CC; ++j) s += __expf(c[j] - m);
    float bg = m + __logf(s) - x0;
    bool pos = labels[idx] > 0;
    unsigned u = __float_as_uint(bg);
    u = (u & 0x80000000u) ? ~u : (u | 0x80000000u);
    u64 key = pos ? 0ull : ((((u64)u) << 32) | (u64)(0xFFFFFFFFu - (unsigned)p));
    keys[idx] = key;
    if (key) atomicAdd(&hist[(b << 16) + (int)(key >> 48)], 1u);
    u64 bal = __ballot(pos);
    if ((tid & 63) == 0) {
        int cnt = __popcll(bal);
        if (cnt) atomicAdd(&numPos[b], cnt);
    }
}

// ---------------- fused selection: suffix-scan + compact + 48-bit radix -> kth key ----------------
// 8 blocks x 1024 threads, one block per batch; phases are per-batch so no cross-block sync.
__global__ void k_sel(const unsigned* __restrict__ hist, const int* __restrict__ numPos,
                      const u64* __restrict__ keys, u64* __restrict__ cand,
                      u64* __restrict__ kth, unsigned* __restrict__ done) {
    int b = blockIdx.x, t = threadIdx.x;
    __shared__ unsigned s[1024];
    __shared__ unsigned h8[256];
    __shared__ unsigned sh_c, sh_k1, sh_hi, sh_rem, sNsh;
    __shared__ u64 sh_pref;

    int np = numPos[b];
    long long kk64 = (long long)np * 15;
    long long neg = (long long)PP - np;
    if (kk64 > neg) kk64 = neg;
    unsigned k = (unsigned)kk64;
    if (k == 0) { if (t == 0) { done[b] = 1u; kth[b] = ~0ull; } return; }

    // --- phase A1: 1024-chunk suffix scan over 64K bins ---
    const unsigned* h = hist + (b << 16);
    unsigned cs = 0;
    const uint4* hv = (const uint4*)(h + (t << 6));
#pragma unroll
    for (int j = 0; j < 16; ++j) { uint4 v = hv[j]; cs += v.x + v.y + v.z + v.w; }
    s[t] = cs; __syncthreads();
    for (int off = 1; off < 1024; off <<= 1) {
        unsigned v = (t + off < 1024) ? s[t + off] : 0u;
        __syncthreads(); s[t] += v; __syncthreads();
    }
    unsigned si = s[t];
    if (si >= k && si - cs < k) { sh_c = (unsigned)t; sh_k1 = k - (si - cs); }
    __syncthreads();
    // --- phase A2: resolve within the winning 64-bin chunk (wave 0) ---
    if (t < 64) {
        unsigned c = sh_c, kk = sh_k1;
        unsigned bin = h[(c << 6) + t];
        unsigned sfx = bin;
        for (int off = 1; off < 64; off <<= 1) {
            unsigned v = __shfl_down(sfx, off, 64);
            if (t + off < 64) sfx += v;
        }
        if (sfx >= kk && sfx - bin < kk) {
            sh_hi  = (c << 6) | (unsigned)t;
            sh_rem = kk - (sfx - bin);
        }
    }
    if (t == 0) { sNsh = 0u; sh_pref = 0ull; }
    __syncthreads();

    // --- phase B: compact keys whose top16 == sh_hi (overwrites this batch's hist bytes) ---
    unsigned hi = sh_hi;
    for (int i = t; i < 65536; i += 1024) {
        u64 key = keys[(b << 16) + i];
        if ((unsigned)(key >> 48) == hi) {
            unsigned pos = atomicAdd(&sNsh, 1u);
            if (pos < 32768u) cand[((size_t)b << 15) + pos] = key;
        }
    }
    __syncthreads();
    unsigned n = sNsh; if (n > 32768u) n = 32768u;

    // --- phase C: 6-pass 8-bit radix over low 48 bits ---
    const u64* cb = cand + ((size_t)b << 15);
    for (int pass = 0; pass < 6; ++pass) {
        int shift = 40 - 8 * pass;
        if (t < 256) h8[t] = 0u;
        __syncthreads();
        u64 prefv = sh_pref;
        unsigned remv = sh_rem;
        u64 himask = (~((1ull << (shift + 8)) - 1ull)) & 0x0000FFFFFFFFFFFFull;
        for (unsigned i = t; i < n; i += 1024) {
            u64 kv = cb[i] & 0x0000FFFFFFFFFFFFull;
            if ((kv & himask) == prefv)
                atomicAdd(&h8[(unsigned)(kv >> shift) & 255u], 1u);
        }
        __syncthreads();
        unsigned binv = (t < 256) ? h8[t] : 0u;
        if (t < 256) s[t] = binv;
        __syncthreads();
        for (int off = 1; off < 256; off <<= 1) {
            unsigned v = (t < 256 && t + off < 256) ? s[t + off] : 0u;
            __syncthreads();
            if (t < 256) s[t] += v;
            __syncthreads();
        }
        if (t < 256) {
            unsigned s2 = s[t];
            if (s2 >= remv && s2 - binv < remv) {
                sh_pref = prefv | ((u64)t << shift);
                sh_rem  = remv - (s2 - binv);
            }
        }
        __syncthreads();
    }
    if (t == 0) kth[b] = ((u64)sh_hi << 48) | sh_pref;
}

// ---------------- fused normalize + MFMA GEMM + logsumexp CE + final reduce ----------------
// M=128/block, N-tiles of 32, direct-from-global A fragments (held in regs/AGPRs),
// post-MFMA row scaling, W double-buffered via gl_lds with counted vmcnt.
__launch_bounds__(256, 3)
__global__ void k_ce(const float* __restrict__ pid, const int* __restrict__ labels,
                     const int* __restrict__ gt, const unsigned short* __restrict__ wswz,
                     const float* __restrict__ bias, const u64* __restrict__ keys,
                     const u64* __restrict__ kth_, const unsigned* __restrict__ done_,
                     float* __restrict__ accum, unsigned* __restrict__ finCnt,
                     float* __restrict__ out) {
    __shared__ __align__(16) char Ws[32768];      // W double buffer: 2 x (32 rows x 512B)
    __shared__ float biasLds[1024];
    __shared__ int gid_s[128];
    __shared__ float mask_s[128];
    __shared__ float fsum[128];
    __shared__ float fgl[128];

    int tid = threadIdx.x;
    int blk = blockIdx.x;              // 1024
    int b = blk >> 7;
    int locBase = (blk & 127) << 7;
    int wv = tid >> 6, lane = tid & 63;
    int l15 = lane & 15, l4 = lane >> 4;
    int kb = l4 << 4;

    // ---- A fragments direct from global (raw bf16) + row norms ----
    short8 af[2][8];
    float rs[2];
    const char* Xb = (const char*)pid + (((size_t)b * 16384 + (size_t)locBase) << 10);
#pragma unroll
    for (int ci = 0; ci < 2; ++ci) {
        const char* xr = Xb + (((size_t)(wv * 32 + ci * 16 + l15)) << 10) + (l4 << 5);
        float ss = 0.f;
#pragma unroll
        for (int ks = 0; ks < 8; ++ks) {
            float4 a  = *(const float4*)(xr + (ks << 7));
            float4 c2 = *(const float4*)(xr + (ks << 7) + 16);
            ss += a.x*a.x + a.y*a.y + a.z*a.z + a.w*a.w
                + c2.x*c2.x + c2.y*c2.y + c2.z*c2.z + c2.w*c2.w;
            short8 v;
            v[0] = (short)f2bf(a.x);  v[1] = (short)f2bf(a.y);
            v[2] = (short)f2bf(a.z);  v[3] = (short)f2bf(a.w);
            v[4] = (short)f2bf(c2.x); v[5] = (short)f2bf(c2.y);
            v[6] = (short)f2bf(c2.z); v[7] = (short)f2bf(c2.w);
            af[ci][ks] = v;
        }
        ss += __shfl_xor(ss, 16, 64);
        ss += __shfl_xor(ss, 32, 64);
        rs[ci] = EMB_SCALE_F / fmaxf(sqrtf(ss), 1e-12f);
    }
    float sc[2][4];
#pragma unroll
    for (int ci = 0; ci < 2; ++ci)
#pragma unroll
        for (int reg = 0; reg < 4; ++reg)
            sc[ci][reg] = __shfl(rs[ci], (l4 << 2) + reg, 64);

    // ---- metadata ----
    if (tid < 128) {
        size_t pb = (size_t)b * PP + ((size_t)(locBase + tid) << 2);
        int g0 = gt[pb], g1 = gt[pb + 1], g2 = gt[pb + 2], g3 = gt[pb + 3];
        int gid = max(max(g0, g1), max(g2, g3));
        u64 kthv = kth_[b];
        unsigned dn = done_[b];
        unsigned msk = 0;
#pragma unroll
        for (int a = 0; a < 4; ++a)
            if (labels[pb + a] > 0 || (!dn && keys[pb + a] >= kthv)) msk = 1u;
        if (gid < 0) msk = 0;
        gid_s[tid] = min(max(gid, 0), NID - 1);
        mask_s[tid] = (float)msk;
    }
#pragma unroll
    for (int i = 0; i < 4; ++i) {
        int idx = tid + (i << 8);
        biasLds[idx] = (idx < NID) ? bias[idx] : -INFINITY;
    }

    // ---- issue W tiles 0,1 (last vmem before loop -> counted vmcnt stays exact) ----
    {
        const char* g0 = (const char*)wswz + (wv << 12) + (lane << 4);
        char* l0 = Ws + (wv << 12);
#pragma unroll
        for (int it = 0; it < 4; ++it) gl_lds16(g0 + (it << 10), l0 + (it << 10));
#pragma unroll
        for (int it = 0; it < 4; ++it) gl_lds16(g0 + 16384 + (it << 10), l0 + 16384 + (it << 10));
    }

    asm volatile("s_waitcnt lgkmcnt(0)" ::: "memory");   // LDS writes visible at first barrier

    float runsum[2][4];
#pragma unroll
    for (int ci = 0; ci < 2; ++ci)
#pragma unroll
        for (int reg = 0; reg < 4; ++reg) runsum[ci][reg] = 0.f;

    int swz = (l15 & 7) << 4;
    const char* r0base = Ws + l15 * 512;
    const char* r1base = Ws + (l15 + 16) * 512;

#pragma unroll 1
    for (int nt = 0; nt < 32; ++nt) {
        if (nt == 31) asm volatile("s_waitcnt vmcnt(0)" ::: "memory");
        else          asm volatile("s_waitcnt vmcnt(4)" ::: "memory");
        asm volatile("s_barrier" ::: "memory");
        int p = (nt & 1) << 14;

        f32x4 a00 = {0,0,0,0}, a01 = {0,0,0,0}, a10 = {0,0,0,0}, a11 = {0,0,0,0};
#pragma unroll
        for (int ks = 0; ks < 8; ++ks) {
            int off = ((((ks << 6) + kb)) ^ swz) + p;
            short8 b0 = *(const short8*)(r0base + off);
            short8 b1 = *(const short8*)(r1base + off);
            a00 = __builtin_amdgcn_mfma_f32_16x16x32_bf16(af[0][ks], b0, a00, 0, 0, 0);
            a01 = __builtin_amdgcn_mfma_f32_16x16x32_bf16(af[0][ks], b1, a01, 0, 0, 0);
            a10 = __builtin_amdgcn_mfma_f32_16x16x32_bf16(af[1][ks], b0, a10, 0, 0, 0);
            a11 = __builtin_amdgcn_mfma_f32_16x16x32_bf16(af[1][ks], b1, a11, 0, 0, 0);
        }
        asm volatile("s_barrier" ::: "memory");           // buf p free for overwrite

        if (nt < 30) {
            const char* gs = (const char*)wswz + ((size_t)(nt + 2) << 14) + (wv << 12) + (lane << 4);
            char* ls = Ws + p + (wv << 12);
#pragma unroll
            for (int it = 0; it < 4; ++it) gl_lds16(gs + (it << 10), ls + (it << 10));
        }

        float bl0 = biasLds[(nt << 5) + l15];
        float bl1 = biasLds[(nt << 5) + 16 + l15];
#pragma unroll
        for (int reg = 0; reg < 4; ++reg) {
            runsum[0][reg] += __expf(fmaf(a00[reg], sc[0][reg], bl0))
                            + __expf(fmaf(a01[reg], sc[0][reg], bl1));
            runsum[1][reg] += __expf(fmaf(a10[reg], sc[1][reg], bl0))
                            + __expf(fmaf(a11[reg], sc[1][reg], bl1));
        }
    }

    // ---- reduce runsum across the 16-lane column groups; direct store ----
#pragma unroll
    for (int o = 1; o <= 8; o <<= 1)
#pragma unroll
        for (int ci = 0; ci < 2; ++ci)
#pragma unroll
            for (int reg = 0; reg < 4; ++reg)
                runsum[ci][reg] += __shfl_xor(runsum[ci][reg], o, 64);
    if (l15 == 0) {
#pragma unroll
        for (int ci = 0; ci < 2; ++ci)
#pragma unroll
            for (int reg = 0; reg < 4; ++reg)
                fsum[wv * 32 + ci * 16 + (l4 << 2) + reg] = runsum[ci][reg];
    }

    // ---- gid-logit via register dot against global W row ----
#pragma unroll
    for (int ci = 0; ci < 2; ++ci) {
        int gid = gid_s[wv * 32 + ci * 16 + l15];
        const char* wr = (const char*)wswz + ((size_t)(gid >> 5) << 14) + ((size_t)(gid & 31) << 9);
        int gsw = (gid & 7) << 4;
        float d = 0.f;
#pragma unroll
        for (int ks = 0; ks < 8; ++ks) {
            short8 w8 = *(const short8*)(wr + ((((ks << 6) + kb)) ^ gsw));
            short8 a8 = af[ci][ks];
#pragma unroll
            for (int j = 0; j < 8; ++j) d = fmaf(bf2f(a8[j]), bf2f(w8[j]), d);
        }
        d += __shfl_xor(d, 16, 64);
        d += __shfl_xor(d, 32, 64);
        if (lane < 16) fgl[wv * 32 + ci * 16 + lane] = fmaf(d, rs[ci], biasLds[gid]);
    }
    __syncthreads();

    if (tid < 128) {
        float ce = __logf(fsum[tid]) - fgl[tid];
        float mm = mask_s[tid];
        float cs2 = ce * mm;
#pragma unroll
        for (int o = 1; o <= 32; o <<= 1) {
            cs2 += __shfl_xor(cs2, o, 64);
            mm  += __shfl_xor(mm, o, 64);
        }
        if (lane == 0) {
            atomicAdd(&accum[0], cs2);
            atomicAdd(&accum[1], mm);
            __threadfence();
        }
    }
    __syncthreads();

    // ---- last block finishes: loss = accum0 / max(accum1, 1) ----
    if (tid == 0) {
        unsigned old = atomicAdd(finCnt, 1u);
        if (old == 1023u) {
            __threadfence();
            float a0 = atomicAdd(&accum[0], 0.0f);
            float a1 = atomicAdd(&accum[1], 0.0f);
            out[0] = a0 / fmaxf(a1, 1.0f);
        }
    }
}

extern "C" void kernel_launch(void* const* d_in, const int* in_sizes, int n_in,
                              void* d_out, int out_size, void* d_ws, size_t ws_size,
                              hipStream_t stream) {
    (void)in_sizes; (void)n_in; (void)out_size; (void)ws_size;
    const float* conf   = (const float*)d_in[0];
    const float* pid    = (const float*)d_in[1];
    const int*   labels = (const int*)d_in[2];
    const int*   gt     = (const int*)d_in[3];
    const float* Wm     = (const float*)d_in[4];
    const float* bias   = (const float*)d_in[5];
    float* out = (float*)d_out;
    char* ws = (char*)d_ws;

    u64* keys           = (u64*)(ws + OFF_KEYS);
    unsigned* hist      = (unsigned*)(ws + OFF_HIST);
    u64* cand           = (u64*)(ws + OFF_HIST);       // phase-B reuse
    unsigned short* wsw = (unsigned short*)(ws + OFF_WSWZ);
    char* st            = ws + OFF_STATE;
    int* numPos         = (int*)(st + ST_NUMPOS);
    unsigned* done      = (unsigned*)(st + ST_DONE);
    u64* kth            = (u64*)(st + ST_KTH);
    float* accum        = (float*)(st + ST_ACCUM);
    unsigned* finCnt    = (unsigned*)(st + ST_FINCNT);

    k_prep<<<2048, 256, 0, stream>>>(Wm, wsw, hist, (unsigned*)st);
    k_keys<<<2048, 256, 0, stream>>>(conf, labels, keys, numPos, hist);
    k_sel <<<8,   1024, 0, stream>>>(hist, numPos, keys, cand, kth, done);
    k_ce  <<<1024, 256, 0, stream>>>(pid, labels, gt, wsw, bias, keys, kth, done,
                                     accum, finCnt, out);
}